// Round 1
// baseline (234.657 us; speedup 1.0000x reference)
//
#include <hip/hip_runtime.h>
#include <hip/hip_bf16.h>

#define NH 32
#define NKVH 8
#define HD 128
#define QT 64
#define KT 64

typedef __attribute__((ext_vector_type(8))) __bf16 bf16x8;
typedef __attribute__((ext_vector_type(4))) float f32x4;
typedef __attribute__((ext_vector_type(2))) unsigned int u32x2;
typedef __attribute__((ext_vector_type(4))) unsigned int u32x4;

__device__ inline unsigned short f2bf(float f) {
    unsigned int u = __builtin_bit_cast(unsigned int, f);
    u += 0x7fffu + ((u >> 16) & 1u);   // RNE
    return (unsigned short)(u >> 16);
}

__device__ inline unsigned int pk2(float lo, float hi) {
    return (unsigned int)f2bf(lo) | ((unsigned int)f2bf(hi) << 16);
}

__device__ inline f32x4 mfma16(bf16x8 a, bf16x8 b, f32x4 c) {
    return __builtin_amdgcn_mfma_f32_16x16x32_bf16(a, b, c, 0, 0, 0);
}

__global__ __launch_bounds__(256) void fa_varlen(
    const float* __restrict__ qg, const float* __restrict__ kg,
    const float* __restrict__ vg, const int* __restrict__ cu,
    float* __restrict__ outg)
{
    const int qt = blockIdx.x, b = blockIdx.y, h = blockIdx.z;
    const int bstart = cu[b];
    const int L = cu[b + 1] - bstart;
    const int q0 = qt * QT;
    if (q0 >= L) return;
    const int kvh = h >> 2;

    const int tid  = threadIdx.x;
    const int wid  = tid >> 6;
    const int lane = tid & 63;
    const int lg = lane >> 4, lr = lane & 15;

    __shared__ __align__(16) unsigned short Klds[KT * HD];    // [j][d] swizzled
    __shared__ __align__(16) unsigned short Vlds[HD * KT];    // [d][j] swizzled (V^T)
    __shared__ __align__(16) unsigned short Plds[4][16 * KT]; // per-wave [q][j] swizzled

    // ---- load Q fragments (A-frag: row = lr, k = lg*8 + i within each 32-slice)
    const int qrow = q0 + wid * 16 + lr;
    const int qtok = bstart + (qrow < L ? qrow : L - 1);
    bf16x8 qf[4];
    #pragma unroll
    for (int kk = 0; kk < 4; ++kk) {
        const float* p = &qg[qtok * (NH * HD) + h * HD + kk * 32 + lg * 8];
        f32x4 a = *(const f32x4*)p;
        f32x4 bq = *(const f32x4*)(p + 4);
        u32x4 r = { pk2(a[0], a[1]), pk2(a[2], a[3]), pk2(bq[0], bq[1]), pk2(bq[2], bq[3]) };
        qf[kk] = __builtin_bit_cast(bf16x8, r);
    }

    f32x4 acc[8];
    #pragma unroll
    for (int i = 0; i < 8; ++i) acc[i] = f32x4{0.f, 0.f, 0.f, 0.f};
    float mrun[4], lrun[4];
    #pragma unroll
    for (int r = 0; r < 4; ++r) { mrun[r] = -1e30f; lrun[r] = 0.f; }

    const float sc = 0.08838834764831843f * 1.4426950408889634f; // 1/sqrt(128) * log2(e)

    const int qmax = (q0 + QT < L) ? (q0 + QT) : L;
    const int ntiles = (qmax + KT - 1) / KT;

    for (int kt = 0; kt < ntiles; ++kt) {
        const int kv0 = kt * KT;

        // ---- stage K tile [64][128] f32 -> bf16 LDS (coalesced float4 reads)
        #pragma unroll
        for (int it = 0; it < 8; ++it) {
            int u = tid + it * 256;          // 2048 float4 units
            int j = u >> 5, c4 = u & 31;
            int jj = kv0 + j;
            f32x4 kx = f32x4{0.f, 0.f, 0.f, 0.f};
            if (jj < L)
                kx = *(const f32x4*)&kg[(bstart + jj) * (NKVH * HD) + kvh * HD + c4 * 4];
            int idx = (j * HD + c4 * 4) ^ ((j & 7) << 3);
            *(u32x2*)&Klds[idx] = u32x2{pk2(kx[0], kx[1]), pk2(kx[2], kx[3])};
        }

        // ---- stage V tile transposed [128][64]: wave w covers row-pairs [w*8, w*8+8)
        #pragma unroll
        for (int it = 0; it < 4; ++it) {
            int jp = wid * 8 + (lane >> 3);
            int c4 = (lane & 7) + it * 8;
            int j0 = jp * 2;
            int jj0 = kv0 + j0;
            f32x4 va = f32x4{0.f, 0.f, 0.f, 0.f}, vbv = f32x4{0.f, 0.f, 0.f, 0.f};
            if (jj0 < L)
                va = *(const f32x4*)&vg[(bstart + jj0) * (NKVH * HD) + kvh * HD + c4 * 4];
            if (jj0 + 1 < L)
                vbv = *(const f32x4*)&vg[(bstart + jj0 + 1) * (NKVH * HD) + kvh * HD + c4 * 4];
            #pragma unroll
            for (int i = 0; i < 4; ++i) {
                int d = c4 * 4 + i;
                int idx = (d * KT + j0) ^ ((d & 7) << 3);
                *(unsigned int*)&Vlds[idx] = pk2(va[i], vbv[i]);
            }
        }
        __syncthreads();

        // ---- S = Q K^T over 4 j-subtiles of 16
        f32x4 sv[4];
        #pragma unroll
        for (int s = 0; s < 4; ++s) {
            f32x4 a = f32x4{0.f, 0.f, 0.f, 0.f};
            int row = s * 16 + lr;
            #pragma unroll
            for (int kk = 0; kk < 4; ++kk) {
                int idx = (row * HD + kk * 32 + lg * 8) ^ ((lr & 7) << 3);
                bf16x8 kf = *(const bf16x8*)&Klds[idx];
                a = mfma16(qf[kk], kf, a);
            }
            sv[s] = a;
        }

        // ---- scale + causal mask + online softmax (rows = lg*4 + r, cols = lr)
        const int qposb = q0 + wid * 16 + lg * 4;
        float tmax[4];
        #pragma unroll
        for (int r = 0; r < 4; ++r) tmax[r] = -1e30f;
        #pragma unroll
        for (int s = 0; s < 4; ++s) {
            int kpos = kv0 + s * 16 + lr;
            #pragma unroll
            for (int r = 0; r < 4; ++r) {
                float x = sv[s][r] * sc;
                x = (kpos <= qposb + r) ? x : -1e30f;
                sv[s][r] = x;
                tmax[r] = fmaxf(tmax[r], x);
            }
        }
        #pragma unroll
        for (int r = 0; r < 4; ++r) {
            float t = tmax[r];
            t = fmaxf(t, __shfl_xor(t, 1));
            t = fmaxf(t, __shfl_xor(t, 2));
            t = fmaxf(t, __shfl_xor(t, 4));
            t = fmaxf(t, __shfl_xor(t, 8));
            float newm = fmaxf(mrun[r], t);
            tmax[r] = exp2f(mrun[r] - newm);  // alpha
            mrun[r] = newm;
        }
        float rsum[4] = {0.f, 0.f, 0.f, 0.f};
        #pragma unroll
        for (int s = 0; s < 4; ++s) {
            #pragma unroll
            for (int r = 0; r < 4; ++r) {
                float p = exp2f(sv[s][r] - mrun[r]);
                sv[s][r] = p;
                rsum[r] += p;
            }
        }
        #pragma unroll
        for (int r = 0; r < 4; ++r) {
            float t = rsum[r];
            t += __shfl_xor(t, 1);
            t += __shfl_xor(t, 2);
            t += __shfl_xor(t, 4);
            t += __shfl_xor(t, 8);
            lrun[r] = lrun[r] * tmax[r] + t;
        }
        #pragma unroll
        for (int dsb = 0; dsb < 8; ++dsb)
            #pragma unroll
            for (int r = 0; r < 4; ++r) acc[dsb][r] *= tmax[r];

        // ---- P -> per-wave LDS (bf16), then O += P V
        unsigned short* Pw = Plds[wid];
        #pragma unroll
        for (int s = 0; s < 4; ++s) {
            #pragma unroll
            for (int r = 0; r < 4; ++r) {
                int prow = lg * 4 + r;
                int idx = (prow * KT + s * 16 + lr) ^ ((prow & 7) << 3);
                Pw[idx] = f2bf(sv[s][r]);
            }
        }
        #pragma unroll
        for (int jc = 0; jc < 2; ++jc) {
            int pidx = (lr * KT + jc * 32 + lg * 8) ^ ((lr & 7) << 3);
            bf16x8 pa = *(const bf16x8*)&Pw[pidx];
            #pragma unroll
            for (int dsb = 0; dsb < 8; ++dsb) {
                int vrow = dsb * 16 + lr;
                int vidx = (vrow * KT + jc * 32 + lg * 8) ^ ((lr & 7) << 3);
                bf16x8 vf = *(const bf16x8*)&Vlds[vidx];
                acc[dsb] = mfma16(pa, vf, acc[dsb]);
            }
        }
        __syncthreads();
    }

    // ---- epilogue: O / l, f32 store
    const int orow = q0 + wid * 16 + lg * 4;
    #pragma unroll
    for (int r = 0; r < 4; ++r) {
        int qr = orow + r;
        if (qr >= L) continue;
        float inv = 1.0f / lrun[r];
        int base = (bstart + qr) * (NH * HD) + h * HD + lr;
        #pragma unroll
        for (int dsb = 0; dsb < 8; ++dsb)
            outg[base + dsb * 16] = acc[dsb][r] * inv;
    }
}

extern "C" void kernel_launch(void* const* d_in, const int* in_sizes, int n_in,
                              void* d_out, int out_size, void* d_ws, size_t ws_size,
                              hipStream_t stream) {
    const float* q = (const float*)d_in[0];
    const float* k = (const float*)d_in[1];
    const float* v = (const float*)d_in[2];
    const int* cu  = (const int*)d_in[3];
    int T = in_sizes[0] / (NH * HD);
    int B = in_sizes[3] - 1;
    int maxtiles = (T + QT - 1) / QT;
    dim3 grid(maxtiles, B, NH);
    fa_varlen<<<grid, dim3(256), 0, stream>>>(q, k, v, cu, (float*)d_out);
}